// Round 1
// baseline (491.044 us; speedup 1.0000x reference)
//
#include <hip/hip_runtime.h>

#define NB 64
#define T 320
#define D 768
#define WD 32
#define BW 81
#define XWPAD 36

// ---------------- K1: projection  xw = x @ Weff^T + beff ----------------
__global__ __launch_bounds__(256) void proj_kernel(
    const float* __restrict__ x, const float* __restrict__ y,
    const float* __restrict__ W, const float* __restrict__ bias,
    const float* __restrict__ wscale, const float* __restrict__ wshift,
    float* __restrict__ xw, float* __restrict__ yw) {
  __shared__ __align__(16) float Wl[WD * D];
  int tid = threadIdx.x;
  for (int i = tid; i < WD * D; i += 256) {
    int k = i / D;
    Wl[i] = W[i] * wscale[k];
  }
  __syncthreads();
  int r = blockIdx.x * 256 + tid;  // 0..2*NB*T-1
  const float* src;
  float* dst;
  if (r < NB * T) { src = x + (size_t)r * D; dst = xw + (size_t)r * WD; }
  else            { src = y + (size_t)(r - NB * T) * D; dst = yw + (size_t)(r - NB * T) * WD; }
  float acc[WD];
#pragma unroll
  for (int k = 0; k < WD; ++k) acc[k] = 0.f;
  const float4* s4 = (const float4*)src;
  const float4* W4 = (const float4*)Wl;
  for (int c = 0; c < D / 4; ++c) {
    float4 xv = s4[c];
#pragma unroll
    for (int k = 0; k < WD; ++k) {
      float4 wv = W4[k * (D / 4) + c];
      acc[k] += xv.x * wv.x + xv.y * wv.y + xv.z * wv.z + xv.w * wv.w;
    }
  }
#pragma unroll
  for (int k = 0; k < WD; ++k) {
    float be = bias[k] * wscale[k] + wshift[k];
    dst[k] = acc[k] + be;
  }
}

// ---------------- K2: banded soft-DTW wavefront DP ----------------
// One block per batch; thread j owns column t2=j. Anti-diagonal d = t1+t2.
// 3-slot LDS diagonal ring -> exactly one __syncthreads per wavefront step.
__global__ __launch_bounds__(T) void dtw_kernel(
    const float* __restrict__ xw, const float* __restrict__ yw,
    float* __restrict__ valbuf) {
  __shared__ __align__(16) float xs[T * XWPAD];
  __shared__ float x2s[T];
  __shared__ float dl[3][T];
  int b = blockIdx.x;
  int j = threadIdx.x;
  const float* xwb = xw + (size_t)b * T * WD;
  const float* ywb = yw + (size_t)b * T * WD;
  // stage xw[b] into LDS (coalesced), padded rows (144B -> 16B aligned)
  for (int i = j; i < T * WD; i += T) {
    int row = i >> 5, col = i & 31;
    xs[row * XWPAD + col] = xwb[i];
  }
  // yw row j lives in registers
  float4 yr[8];
#pragma unroll
  for (int q = 0; q < 8; ++q) yr[q] = ((const float4*)(ywb + (size_t)j * WD))[q];
  float y2 = 0.f;
#pragma unroll
  for (int q = 0; q < 8; ++q)
    y2 += yr[q].x * yr[q].x + yr[q].y * yr[q].y + yr[q].z * yr[q].z + yr[q].w * yr[q].w;
  __syncthreads();
  {
    float s = 0.f;
#pragma unroll
    for (int q = 0; q < 8; ++q) {
      float4 v = *((const float4*)&xs[j * XWPAD + q * 4]);
      s += v.x * v.x + v.y * v.y + v.z * v.z + v.w * v.w;
    }
    x2s[j] = s;
  }
  __syncthreads();
  float* out = valbuf + (size_t)b * T * T;
  float up_reg = 0.f;
  for (int d = 0; d < 2 * T - 1; ++d) {
    int t1 = d - j;
    if (0 <= t1 && t1 < T) {
      float val = 0.f;
      int dj = t1 - j;  // in band: t2 >= t1-81 && t2 <= t1+80
      bool in_band = (dj <= BW) && (dj >= -(BW - 1));
      if (in_band) {
        float dot = 0.f;
        const float4* xr = (const float4*)&xs[t1 * XWPAD];
#pragma unroll
        for (int q = 0; q < 8; ++q) {
          float4 v = xr[q];
          dot += v.x * yr[q].x + v.y * yr[q].y + v.z * yr[q].z + v.w * yr[q].w;
        }
        float dist = x2s[t1] + y2 - 2.f * dot;
        if (d == 0) {
          val = dist;
        } else {
          int p1 = (d + 2) % 3;  // diag d-1
          int p2 = (d + 1) % 3;  // diag d-2
          float cd = (t1 > 0 && j > 0) ? dl[p2][j - 1] : 1e30f;
          float cu = (t1 > 0) ? up_reg : 1e30f;
          float cl = (j > 0) ? dl[p1][j - 1] : 1e30f;
          float m = fminf(cd, fminf(cu, cl));
          float ssum = __expf(m - cd) + __expf(m - cu) + __expf(m - cl);
          val = dist + m - __logf(ssum);
        }
      }
      dl[d % 3][j] = val;
      up_reg = val;
      out[(size_t)t1 * T + j] = val;
    }
    __syncthreads();
  }
}

// ---------------- K3: row softmax of -val, in place ----------------
__global__ __launch_bounds__(T) void softmax_kernel(float* __restrict__ path) {
  __shared__ float sm1[5], sm2[5];
  size_t row = blockIdx.x;
  int j = threadIdx.x;
  float* p = path + row * T;
  float v = p[j];
  float m = v;
#pragma unroll
  for (int off = 32; off >= 1; off >>= 1) m = fminf(m, __shfl_xor(m, off, 64));
  int w = j >> 6;
  if ((j & 63) == 0) sm1[w] = m;
  __syncthreads();
  m = fminf(fminf(fminf(sm1[0], sm1[1]), fminf(sm1[2], sm1[3])), sm1[4]);
  float e = __expf(m - v);  // exp(-v - max(-v))
  float s = e;
#pragma unroll
  for (int off = 32; off >= 1; off >>= 1) s += __shfl_xor(s, off, 64);
  if ((j & 63) == 0) sm2[w] = s;
  __syncthreads();
  s = sm2[0] + sm2[1] + sm2[2] + sm2[3] + sm2[4];
  p[j] = e / s;
}

// ---------------- K3b: column sums -> scale = 1/(colsum+1e-10) ----------------
__global__ __launch_bounds__(T) void colsum_kernel(
    const float* __restrict__ path, float* __restrict__ scale) {
  int b = blockIdx.x;
  int j = threadIdx.x;
  const float* p = path + (size_t)b * T * T;
  float s = 0.f;
  for (int t = 0; t < T; ++t) s += p[(size_t)t * T + j];
  scale[b * T + j] = 1.f / (s + 1e-10f);
}

// ---------------- K4: aligned[b,s,d] = scale[b,s] * sum_t P[b,t,s]*x[b,t,d] ----------------
#define TS 64
#define TDD 128
#define TK 16
__global__ __launch_bounds__(256) void bmm_kernel(
    const float* __restrict__ path, const float* __restrict__ x,
    const float* __restrict__ scale, float* __restrict__ out) {
  __shared__ __align__(16) float Pl[TK][TS];
  __shared__ __align__(16) float Xl[TK][TDD];
  int b = blockIdx.z;
  int s0 = blockIdx.y * TS;
  int d0 = blockIdx.x * TDD;
  int tid = threadIdx.x;
  int ts = tid & 15, td = tid >> 4;
  const float* pb = path + (size_t)b * T * T;
  const float* xb = x + (size_t)b * T * D;
  float acc[4][8];
#pragma unroll
  for (int i = 0; i < 4; ++i)
#pragma unroll
    for (int jj = 0; jj < 8; ++jj) acc[i][jj] = 0.f;
  for (int t0 = 0; t0 < T; t0 += TK) {
    __syncthreads();
    {  // stage P: 16x64
      int tr = tid >> 4;
      int sc = (tid & 15) * 4;
      *((float4*)&Pl[tr][sc]) = *((const float4*)&pb[(size_t)(t0 + tr) * T + s0 + sc]);
    }
    {  // stage X: 16x128
      int tr = tid >> 5;
      int dc = (tid & 31) * 4;
      *((float4*)&Xl[tr][dc]) = *((const float4*)&xb[(size_t)(t0 + tr) * D + d0 + dc]);
      *((float4*)&Xl[tr + 8][dc]) = *((const float4*)&xb[(size_t)(t0 + tr + 8) * D + d0 + dc]);
    }
    __syncthreads();
#pragma unroll
    for (int t = 0; t < TK; ++t) {
      float4 pv = *((const float4*)&Pl[t][ts * 4]);
      float4 xa = *((const float4*)&Xl[t][td * 8]);
      float4 xc = *((const float4*)&Xl[t][td * 8 + 4]);
      float pvv[4] = {pv.x, pv.y, pv.z, pv.w};
      float xvv[8] = {xa.x, xa.y, xa.z, xa.w, xc.x, xc.y, xc.z, xc.w};
#pragma unroll
      for (int i = 0; i < 4; ++i)
#pragma unroll
        for (int jj = 0; jj < 8; ++jj) acc[i][jj] += pvv[i] * xvv[jj];
    }
  }
#pragma unroll
  for (int i = 0; i < 4; ++i) {
    int s = s0 + ts * 4 + i;
    float sc = scale[b * T + s];
    float4 o0, o1;
    o0.x = acc[i][0] * sc; o0.y = acc[i][1] * sc; o0.z = acc[i][2] * sc; o0.w = acc[i][3] * sc;
    o1.x = acc[i][4] * sc; o1.y = acc[i][5] * sc; o1.z = acc[i][6] * sc; o1.w = acc[i][7] * sc;
    float* op = out + ((size_t)b * T + s) * D + d0 + td * 8;
    *((float4*)op) = o0;
    *((float4*)(op + 4)) = o1;
  }
}

extern "C" void kernel_launch(void* const* d_in, const int* in_sizes, int n_in,
                              void* d_out, int out_size, void* d_ws, size_t ws_size,
                              hipStream_t stream) {
  const float* x = (const float*)d_in[0];
  const float* y = (const float*)d_in[1];
  const float* W = (const float*)d_in[2];
  const float* bias = (const float*)d_in[3];
  const float* wscale = (const float*)d_in[4];
  const float* wshift = (const float*)d_in[5];
  float* outp = (float*)d_out;
  float* aligned = outp;                          // [B,T,D]
  float* path = outp + (size_t)NB * T * D;        // [B,T,T] (raw vals -> probs in place)
  float* ws = (float*)d_ws;
  float* xw = ws;
  float* yw = xw + (size_t)NB * T * WD;
  float* scale = yw + (size_t)NB * T * WD;        // [B,T]

  proj_kernel<<<dim3((2 * NB * T) / 256), 256, 0, stream>>>(x, y, W, bias, wscale, wshift, xw, yw);
  dtw_kernel<<<dim3(NB), T, 0, stream>>>(xw, yw, path);
  softmax_kernel<<<dim3(NB * T), T, 0, stream>>>(path);
  colsum_kernel<<<dim3(NB), T, 0, stream>>>(path, scale);
  bmm_kernel<<<dim3(D / TDD, T / TS, NB), 256, 0, stream>>>(path, x, scale, aligned);
}